// Round 10
// baseline (303.592 us; speedup 1.0000x reference)
//
#include <hip/hip_runtime.h>
#include <math.h>

#define KDD 192

typedef __attribute__((ext_vector_type(8))) short bfrag;   // 8 bf16
typedef __attribute__((ext_vector_type(4))) float facc;    // 4 fp32

__device__ inline unsigned short bf16r(float x) {
  union { float f; unsigned u; } v; v.f = x;
  unsigned r = v.u + 0x7fffu + ((v.u >> 16) & 1u);
  return (unsigned short)(r >> 16);
}
__device__ inline float bf2f(unsigned short h) {
  union { unsigned u; float f; } v; v.u = ((unsigned)h) << 16; return v.f;
}
__device__ inline float gelu_f(float x) {
  return x * 0.5f * (1.f + erff(x * 0.70710678f));
}
// async global->LDS, 16B per lane; LDS dest = wave-uniform base + lane*16
__device__ __forceinline__ void gload16(const void* g, void* l) {
  __builtin_amdgcn_global_load_lds((const __attribute__((address_space(1))) unsigned int*)g,
                                   (__attribute__((address_space(3))) unsigned int*)l,
                                   16, 0, 0);
}

// ---------------- mega phase-A kernel: LN + weight-prep + Wc GEMM + RoPE tables + stat-zero ----
__global__ __launch_bounds__(256) void k_lnw(const float* __restrict__ x,
                                             const float* __restrict__ g,
                                             const float* __restrict__ bb,
                                             unsigned short* __restrict__ y,
                                             const float* __restrict__ Wv,
                                             const float* __restrict__ Wo1,
                                             const float* __restrict__ Wo2,
                                             unsigned short* __restrict__ WvT,
                                             unsigned short* __restrict__ Wo1T,
                                             unsigned short* __restrict__ Wo2T,
                                             float* __restrict__ scol,
                                             const float* __restrict__ Win,
                                             const float* __restrict__ pxW,
                                             const float* __restrict__ pyW,
                                             float* __restrict__ Wcx,
                                             float* __restrict__ Wcy,
                                             const float* __restrict__ pos_x,
                                             const float* __restrict__ pos_y,
                                             float* __restrict__ tabx,
                                             float* __restrict__ taby,
                                             float* __restrict__ sbuf) {
  __shared__ float As[16][64];
  __shared__ float Bs[16][64];
  int bid = blockIdx.x, t = threadIdx.x;
  if (bid < 16384) {
    int w = t >> 6, lane = t & 63;
    size_t row = (size_t)bid * 4 + w;
    float2 v = *(const float2*)(x + row * 128 + lane * 2);
    float s = v.x + v.y, s2 = v.x * v.x + v.y * v.y;
#pragma unroll
    for (int off = 1; off < 64; off <<= 1) {
      s += __shfl_xor(s, off, 64);
      s2 += __shfl_xor(s2, off, 64);
    }
    float mean = s * (1.f / 128.f);
    float var = s2 * (1.f / 128.f) - mean * mean;
    float r = rsqrtf(var + 1e-5f);
    float2 gg = *(const float2*)(g + lane * 2);
    float2 bv = *(const float2*)(bb + lane * 2);
    unsigned h0 = bf16r((v.x - mean) * r * gg.x + bv.x);
    unsigned h1 = bf16r((v.y - mean) * r * gg.y + bv.y);
    *(unsigned*)(y + row * 128 + lane * 2) = h0 | (h1 << 16);
    return;
  }
  if (bid < 16961) {
    int blk = bid - 16384;
    if (blk < 256) {
      int idx = blk * 256 + t;            // 65536: WvT[hc][d] = Wv[d][hc]
      int c = idx >> 7, r = idx & 127;
      WvT[(size_t)c * 128 + r] = bf16r(Wv[(size_t)r * 512 + c]);
    } else if (blk < 512) {
      int idx = (blk - 256) * 256 + t;    // 65536: Wo1T[n][k] = Wo1[k][n]
      int n = idx >> 9, k = idx & 511;
      Wo1T[(size_t)n * 512 + k] = bf16r(Wo1[(size_t)k * 128 + n]);
    } else if (blk < 576) {
      int idx = (blk - 512) * 256 + t;    // 16384: Wo2T[n][k] = Wo2[k][n]
      int n = idx >> 7, k = idx & 127;
      Wo2T[n * 128 + k] = bf16r(Wo2[k * 128 + n]);
    } else {
      if (t < 128) {
        float a = 0;
        for (int k = 0; k < 512; k++) a += bf2f(bf16r(Wo1[k * 128 + t]));
        scol[t] = a;
      }
    }
    return;
  }
  if (bid < 16969) {
    int idx = bid - 16961;                 // 0..7
    int n0 = (idx & 1) * 64, m0 = ((idx >> 1) & 1) * 64;
    const float* A = Win;
    const float* Bm = (idx >> 2) ? pyW : pxW;
    float* C = (idx >> 2) ? Wcy : Wcx;
    int tx = t & 15, ty = t >> 4;
    float acc[4][4] = {};
    int la_m = t >> 2, la_k = (t & 3) * 4;
    int lb_k = t >> 4, lb_n = (t & 15) * 4;
    for (int k0 = 0; k0 < 128; k0 += 16) {
      float4 a4 = *(const float4*)(A + (size_t)(m0 + la_m) * 128 + k0 + la_k);
      As[la_k + 0][la_m] = a4.x; As[la_k + 1][la_m] = a4.y;
      As[la_k + 2][la_m] = a4.z; As[la_k + 3][la_m] = a4.w;
      float4 b4 = *(const float4*)(Bm + (size_t)(k0 + lb_k) * 128 + n0 + lb_n);
      *(float4*)&Bs[lb_k][lb_n] = b4;
      __syncthreads();
#pragma unroll
      for (int kk = 0; kk < 16; kk++) {
        float4 av = *(const float4*)&As[kk][ty * 4];
        float4 bv = *(const float4*)&Bs[kk][tx * 4];
        float a[4] = {av.x, av.y, av.z, av.w};
        float b[4] = {bv.x, bv.y, bv.z, bv.w};
#pragma unroll
        for (int i = 0; i < 4; i++)
#pragma unroll
          for (int j = 0; j < 4; j++) acc[i][j] += a[i] * b[j];
      }
      __syncthreads();
    }
#pragma unroll
    for (int i = 0; i < 4; i++) {
      float4 o;
      o.x = acc[i][0]; o.y = acc[i][1]; o.z = acc[i][2]; o.w = acc[i][3];
      *(float4*)(C + (size_t)(m0 + ty * 4 + i) * 128 + n0 + tx * 4) = o;
    }
    return;
  }
  if (bid < 17065) {
    int id = (bid - 16969) * 256 + t;      // 0..24575
    int axis = id >= 12288;
    int rem = axis ? id - 12288 : id;
    int n = rem / 96, fi = rem - n * 96;
    const float* pos = axis ? pos_y : pos_x;
    float inv = expf(-logf(10000.f) * ((float)fi / 96.f));
    float f = pos[n] * 64.f * inv;
    float2 cssn;
    cssn.x = cosf(f);
    cssn.y = sinf(f);
    ((float2*)(axis ? taby : tabx))[n * 96 + fi] = cssn;
    return;
  }
  {
    float4 z4 = {0.f, 0.f, 0.f, 0.f};
    ((float4*)sbuf)[t] = z4;               // 256 * 16B = 1024 floats (sbuf+s2buf)
  }
}

// ---------------- merged vt + pooling-MLP launch ----------------
// blocks [0,512): vt (un tile staged once, 4 mt per block)
// blocks [512,1024): pool2, 2 (sel,row) units per 256-thr block.
// pool2 loops use explicit 8-wide load batching (same FMA order -> bit-identical,
// but loads issue in groups of 8 so the latency chain is 8x shorter).
__global__ __launch_bounds__(256) void k_pvt(const unsigned short* __restrict__ WvT,
                                             const unsigned short* __restrict__ un,
                                             unsigned short* __restrict__ vT,
                                             const float* __restrict__ Wc0, const float* __restrict__ Wc1,
                                             const float* __restrict__ g0, const float* __restrict__ g1,
                                             const float* __restrict__ bb0, const float* __restrict__ bb1,
                                             const float* __restrict__ W10, const float* __restrict__ W11,
                                             const float* __restrict__ b10, const float* __restrict__ b11,
                                             const float* __restrict__ W20, const float* __restrict__ W21,
                                             const float* __restrict__ b20, const float* __restrict__ b21,
                                             float* __restrict__ o0, float* __restrict__ o1) {
  __shared__ __align__(16) unsigned short Bs[16384];
  __shared__ float xin[2][128], h1[2][128], h3[2][128];
  __shared__ float ps[2][2], ps2[2][2];
  int bid = blockIdx.x;
  int tid = threadIdx.x;
  if (bid < 512) {
    // ---- vt ----
    int nt = bid;
    int w = tid >> 6, lane = tid & 63, quad = lane >> 4, l16 = lane & 15;
    int wr = w >> 1, wc = w & 1;
    {
      const unsigned short* sbp = un + (size_t)nt * 16384;
#pragma unroll
      for (int q = 0; q < 8; q++) {
        int rbase = w * 32 + q * 4;
        int r = rbase + quad;
        gload16(sbp + (size_t)r * 128 + ((l16 ^ (r & 15)) << 3), &Bs[rbase * 128]);
      }
    }
    __syncthreads();
    facc zf = {0.f, 0.f, 0.f, 0.f};
#pragma unroll
    for (int mt = 0; mt < 4; mt++) {
      const unsigned short* ap = WvT + (size_t)mt * 128 * 128;
      facc acc[4][4];
#pragma unroll
      for (int lt = 0; lt < 4; lt++)
#pragma unroll
        for (int xt = 0; xt < 4; xt++) acc[lt][xt] = zf;
#pragma unroll
      for (int k0 = 0; k0 < 4; k0++) {
        int chunk = ((k0 * 4 + quad) ^ l16) << 3;
        bfrag bv[4], av[4];
#pragma unroll
        for (int lt = 0; lt < 4; lt++)
          bv[lt] = *(const bfrag*)&Bs[((wc * 4 + lt) * 16 + l16) * 128 + chunk];
#pragma unroll
        for (int xt = 0; xt < 4; xt++)
          av[xt] = *(const bfrag*)(ap + (size_t)((wr * 4 + xt) * 16 + l16) * 128 + k0 * 32 + quad * 8);
        __builtin_amdgcn_s_setprio(1);
#pragma unroll
        for (int lt = 0; lt < 4; lt++)
#pragma unroll
          for (int xt = 0; xt < 4; xt++)
            acc[lt][xt] = __builtin_amdgcn_mfma_f32_16x16x32_bf16(bv[lt], av[xt], acc[lt][xt], 0, 0, 0);
        __builtin_amdgcn_s_setprio(0);
      }
#pragma unroll
      for (int xt = 0; xt < 4; xt++) {
        int hc = mt * 128 + (wr * 4 + xt) * 16 + l16;
        unsigned short* dst = vT + (size_t)hc * 65536 + nt * 128 + quad * 4;
#pragma unroll
        for (int lt = 0; lt < 4; lt++) {
          facc a = acc[lt][xt];
          uint2 p;
          p.x = (unsigned)bf16r(a[0]) | ((unsigned)bf16r(a[1]) << 16);
          p.y = (unsigned)bf16r(a[2]) | ((unsigned)bf16r(a[3]) << 16);
          *(uint2*)(dst + (wc * 4 + lt) * 16) = p;
        }
      }
    }
    return;
  }
  // ---- pool2: 2 units per block ----
  int u2 = tid >> 7;                      // sub-unit 0/1
  int t = tid & 127;
  int unit = (bid - 512) * 2 + u2;        // 0..1023
  int sel = unit >> 9, row = unit & 511;
  const float* Wc = sel ? Wc1 : Wc0;
  const float* g = sel ? g1 : g0;     const float* bb = sel ? bb1 : bb0;
  const float* W1 = sel ? W11 : W10;  const float* b1 = sel ? b11 : b10;
  const float* W2 = sel ? W21 : W20;  const float* b2 = sel ? b21 : b20;
  float* out = sel ? o1 : o0;
  // fused k_means: identical summation order, loads batched 8-wide
  {
    float s0 = 0.f;
    const unsigned short* p;
    size_t stride;
    if (sel == 0) {
      p = un + (size_t)row * 16384 + t;
      stride = 128;
    } else {
      int b = row >> 7, j = row & 127;
      p = un + (size_t)b * 2097152 + (size_t)j * 128 + t;
      stride = 16384;
    }
    for (int j0 = 0; j0 < 128; j0 += 8) {
      unsigned short vb[8];
#pragma unroll
      for (int e = 0; e < 8; e++) vb[e] = p[(size_t)(j0 + e) * stride];
#pragma unroll
      for (int e = 0; e < 8; e++) s0 += bf2f(vb[e]);
    }
    xin[u2][t] = s0 * (1.f / 128.f);
  }
  __syncthreads();
  float a = 0;
  for (int k0 = 0; k0 < 128; k0 += 8) {
    float wv[8];
#pragma unroll
    for (int e = 0; e < 8; e++) wv[e] = Wc[(k0 + e) * 128 + t];
#pragma unroll
    for (int e = 0; e < 8; e++) a += xin[u2][k0 + e] * wv[e];
  }
  float s = a, s2 = a * a;
  for (int off = 32; off > 0; off >>= 1) {
    s += __shfl_down(s, off, 64);
    s2 += __shfl_down(s2, off, 64);
  }
  if ((t & 63) == 0) { ps[u2][t >> 6] = s; ps2[u2][t >> 6] = s2; }
  __syncthreads();
  float S = ps[u2][0] + ps[u2][1], S2 = ps2[u2][0] + ps2[u2][1];
  float mean = S * (1.f / 128.f);
  float var = S2 * (1.f / 128.f) - mean * mean;
  float r = rsqrtf(var + 1e-5f);
  h1[u2][t] = (a - mean) * r * g[t] + bb[t];
  __syncthreads();
  float u1 = b1[t], uu2 = b1[t + 128];
  for (int k0 = 0; k0 < 128; k0 += 8) {
    float wa[8], wb[8];
#pragma unroll
    for (int e = 0; e < 8; e++) {
      wa[e] = W1[(k0 + e) * 256 + t];
      wb[e] = W1[(k0 + e) * 256 + t + 128];
    }
#pragma unroll
    for (int e = 0; e < 8; e++) {
      float hv = h1[u2][k0 + e];
      u1 += hv * wa[e];
      uu2 += hv * wb[e];
    }
  }
  h3[u2][t] = gelu_f(u1) * uu2;
  __syncthreads();
  if (t < 64) {
    float o = b2[t];
    for (int k0 = 0; k0 < 128; k0 += 8) {
      float wv[8];
#pragma unroll
      for (int e = 0; e < 8; e++) wv[e] = W2[(k0 + e) * 64 + t];
#pragma unroll
      for (int e = 0; e < 8; e++) o += h3[u2][k0 + e] * wv[e];
    }
    out[(size_t)row * 64 + t] = o;
  }
}

// ---------------- fp32 GEMM, z-batched (qk projection) ----------------
__global__ __launch_bounds__(256) void k_gemmz(const float* __restrict__ A0,
                                               const float* __restrict__ B0,
                                               float* __restrict__ C0,
                                               const float* __restrict__ A1,
                                               const float* __restrict__ B1,
                                               float* __restrict__ C1,
                                               int K, int lda, int ldb, int ldc) {
  const float* A = blockIdx.z ? A1 : A0;
  const float* Bm = blockIdx.z ? B1 : B0;
  float* C = blockIdx.z ? C1 : C0;
  __shared__ float As[16][64];
  __shared__ float Bs[16][64];
  int tid = threadIdx.x;
  int n0 = blockIdx.x * 64, m0 = blockIdx.y * 64;
  int tx = tid & 15, ty = tid >> 4;
  float acc[4][4] = {};
  int la_m = tid >> 2, la_k = (tid & 3) * 4;
  int lb_k = tid >> 4, lb_n = (tid & 15) * 4;
  for (int k0 = 0; k0 < K; k0 += 16) {
    float4 a4 = *(const float4*)(A + (size_t)(m0 + la_m) * lda + k0 + la_k);
    As[la_k + 0][la_m] = a4.x; As[la_k + 1][la_m] = a4.y;
    As[la_k + 2][la_m] = a4.z; As[la_k + 3][la_m] = a4.w;
    float4 b4 = *(const float4*)(Bm + (size_t)(k0 + lb_k) * ldb + n0 + lb_n);
    *(float4*)&Bs[lb_k][lb_n] = b4;
    __syncthreads();
#pragma unroll
    for (int kk = 0; kk < 16; kk++) {
      float4 av = *(const float4*)&As[kk][ty * 4];
      float4 bv = *(const float4*)&Bs[kk][tx * 4];
      float a[4] = {av.x, av.y, av.z, av.w};
      float b[4] = {bv.x, bv.y, bv.z, bv.w};
#pragma unroll
      for (int i = 0; i < 4; i++)
#pragma unroll
        for (int j = 0; j < 4; j++) acc[i][j] += a[i] * b[j];
    }
    __syncthreads();
  }
#pragma unroll
  for (int i = 0; i < 4; i++) {
    float4 o;
    o.x = acc[i][0]; o.y = acc[i][1]; o.z = acc[i][2]; o.w = acc[i][3];
    *(float4*)(C + (size_t)(m0 + ty * 4 + i) * ldc + n0 + tx * 4) = o;
  }
}

// ---------------- batched Q@K^T with fused rotary staging, z-batched x/y ----------------
__global__ __launch_bounds__(512) void k_qkt2(const float* __restrict__ qk0, const float* __restrict__ qk1,
                                              const float* __restrict__ tab0, const float* __restrict__ tab1,
                                              unsigned short* __restrict__ C0,
                                              unsigned short* __restrict__ C1) {
  int z = blockIdx.z;
  int bh = z & 31;
  int b = bh >> 3, h = bh & 7;
  const float* qk = (z < 32) ? qk0 : qk1;
  const float* tab = (z < 32) ? tab0 : tab1;
  unsigned short* Cb = ((z < 32) ? C0 : C1) + (size_t)bh * 16384;
  __shared__ float As[16][64];
  __shared__ float Bs[16][64];
  int tid = threadIdx.x;
  int i0 = blockIdx.y * 64, j0 = blockIdx.x * 64;
  int tx = tid & 15, ty = tid >> 4;
  float acc[2][4] = {};
  int l_m = tid >> 3, l_k = (tid & 7) * 2;
  for (int k0 = 0; k0 < KDD; k0 += 16) {
    int d = k0 + l_k;                    // even, 0..190
    int fi = d < 96 ? d : d - 96;
    float sgn = d < 96 ? -1.f : 1.f;
    int prt = d < 96 ? d + 96 : d - 96;
    {
      int n = i0 + l_m;
      const float* src = qk + (size_t)(b * 128 + n) * 3072 + h * 192;
      float2 qd = *(const float2*)(src + d);
      float2 qp = *(const float2*)(src + prt);
      float2 t0 = *(const float2*)(tab + (size_t)(n * 96 + fi) * 2);
      float2 t1 = *(const float2*)(tab + (size_t)(n * 96 + fi + 1) * 2);
      As[l_k + 0][l_m] = qd.x * t0.x + sgn * qp.x * t0.y;
      As[l_k + 1][l_m] = qd.y * t1.x + sgn * qp.y * t1.y;
    }
    {
      int n = j0 + l_m;
      const float* src = qk + (size_t)(b * 128 + n) * 3072 + 1536 + h * 192;
      float2 qd = *(const float2*)(src + d);
      float2 qp = *(const float2*)(src + prt);
      float2 t0 = *(const float2*)(tab + (size_t)(n * 96 + fi) * 2);
      float2 t1 = *(const float2*)(tab + (size_t)(n * 96 + fi + 1) * 2);
      Bs[l_k + 0][l_m] = qd.x * t0.x + sgn * qp.x * t0.y;
      Bs[l_k + 1][l_m] = qd.y * t1.x + sgn * qp.y * t1.y;
    }
    __syncthreads();
#pragma unroll
    for (int kk = 0; kk < 16; kk++) {
      float2 av = *(const float2*)&As[kk][ty * 2];
      float4 bv = *(const float4*)&Bs[kk][tx * 4];
      float a[2] = {av.x, av.y};
      float b2[4] = {bv.x, bv.y, bv.z, bv.w};
#pragma unroll
      for (int i = 0; i < 2; i++)
#pragma unroll
        for (int j = 0; j < 4; j++) acc[i][j] += a[i] * b2[j];
    }
    __syncthreads();
  }
#pragma unroll
  for (int i = 0; i < 2; i++) {
    unsigned h0 = bf16r(acc[i][0]), h1 = bf16r(acc[i][1]);
    unsigned h2 = bf16r(acc[i][2]), h3 = bf16r(acc[i][3]);
    uint2 pk;
    pk.x = h0 | (h1 << 16);
    pk.y = h2 | (h3 << 16);
    *(uint2*)(Cb + (size_t)(i0 + ty * 2 + i) * 128 + j0 + tx * 4) = pk;
  }
}

// ==== xor-swizzled LDS helpers: logical (row 0..127, col 0..127) on a 128x128 ushort tile ====
// phys = row*128 + ((c8 ^ (row&15))<<3) + (col&7), c8 = col>>3

// ---- fused x/y attend per (bh, 4-c strip): tt'[bh][c][i][l] = kx @ (Vc @ ky^T), + stats ----
// (R1-benched version: Ky staged once in LDS, V via gload_lds at loop top — ~41 us)
__global__ __launch_bounds__(256, 2) void k_fuse12(const unsigned short* __restrict__ kxall,
                                                   const unsigned short* __restrict__ kyall,
                                                   const unsigned short* __restrict__ vT,
                                                   unsigned short* __restrict__ ttp,
                                                   float* __restrict__ sb,
                                                   float* __restrict__ s2b) {
  int blk = blockIdx.x;            // 512
  int bh = blk >> 4, strip = blk & 15;
  int b = bh >> 3, h = bh & 7;
  __shared__ __align__(16) unsigned short Ky[16384];
  __shared__ __align__(16) unsigned short Vs[16384];
  int tid = threadIdx.x;
  int w = tid >> 6, lane = tid & 63, quad = lane >> 4, l16 = lane & 15;
  int wr = w >> 1, wc = w & 1;

  {
    const unsigned short* kb = kyall + (size_t)bh * 16384;
#pragma unroll
    for (int q = 0; q < 8; q++) {
      int rbase = w * 32 + q * 4;
      int r = rbase + quad;
      gload16(kb + (size_t)r * 128 + ((l16 ^ (r & 15)) << 3), &Ky[rbase * 128]);
    }
  }
  bfrag axf[4][4];
  {
    const unsigned short* xb = kxall + (size_t)bh * 16384;
#pragma unroll
    for (int it = 0; it < 4; it++) {
      int i = (wr * 4 + it) * 16 + l16;
#pragma unroll
      for (int k0 = 0; k0 < 4; k0++)
        axf[it][k0] = *(const bfrag*)(xb + (size_t)i * 128 + k0 * 32 + quad * 8);
    }
  }

  float s[4] = {0.f, 0.f, 0.f, 0.f}, s2[4] = {0.f, 0.f, 0.f, 0.f};
  facc zf = {0.f, 0.f, 0.f, 0.f};

  for (int cc = 0; cc < 4; cc++) {
    int c = strip * 4 + cc;
    if (cc) __syncthreads();
    {
      const unsigned short* vb = vT + (size_t)(h * 64 + c) * 65536 + (size_t)b * 16384;
#pragma unroll
      for (int q = 0; q < 8; q++) {
        int rbase = w * 32 + q * 4;
        int r = rbase + quad;
        gload16(vb + (size_t)r * 128 + ((l16 ^ (r & 15)) << 3), &Vs[rbase * 128]);
      }
    }
    __syncthreads();

    facc a1[4][4];
#pragma unroll
    for (int xt = 0; xt < 4; xt++)
#pragma unroll
      for (int lt = 0; lt < 4; lt++) a1[xt][lt] = zf;
#pragma unroll
    for (int k0 = 0; k0 < 4; k0++) {
      int chunk = ((k0 * 4 + quad) ^ l16) << 3;
      bfrag av[4], bv[4];
#pragma unroll
      for (int xt = 0; xt < 4; xt++)
        av[xt] = *(const bfrag*)&Vs[((wr * 4 + xt) * 16 + l16) * 128 + chunk];
#pragma unroll
      for (int lt = 0; lt < 4; lt++)
        bv[lt] = *(const bfrag*)&Ky[((wc * 4 + lt) * 16 + l16) * 128 + chunk];
      __builtin_amdgcn_s_setprio(1);
#pragma unroll
      for (int xt = 0; xt < 4; xt++)
#pragma unroll
        for (int lt = 0; lt < 4; lt++)
          a1[xt][lt] = __builtin_amdgcn_mfma_f32_16x16x32_bf16(av[xt], bv[lt], a1[xt][lt], 0, 0, 0);
      __builtin_amdgcn_s_setprio(0);
    }
    __syncthreads();
#pragma unroll
    for (int xt = 0; xt < 4; xt++) {
      int xc = (wr * 4 + xt) * 2 + (quad >> 1);
      int xo = (quad & 1) * 4;
#pragma unroll
      for (int lt = 0; lt < 4; lt++) {
        int l = (wc * 4 + lt) * 16 + l16;
        unsigned p0 = (unsigned)bf16r(a1[xt][lt][0]) | ((unsigned)bf16r(a1[xt][lt][1]) << 16);
        unsigned p1 = (unsigned)bf16r(a1[xt][lt][2]) | ((unsigned)bf16r(a1[xt][lt][3]) << 16);
        uint2 p; p.x = p0; p.y = p1;
        *(uint2*)&Vs[l * 128 + ((xc ^ (l & 15)) << 3) + xo] = p;
      }
    }
    __syncthreads();

    facc a2[4][4];
#pragma unroll
    for (int st = 0; st < 4; st++)
#pragma unroll
      for (int it = 0; it < 4; it++) a2[st][it] = zf;
#pragma unroll
    for (int k0 = 0; k0 < 4; k0++) {
      int chunk = ((k0 * 4 + quad) ^ l16) << 3;
      bfrag sv[4];
#pragma unroll
      for (int st = 0; st < 4; st++)
        sv[st] = *(const bfrag*)&Vs[((wc * 4 + st) * 16 + l16) * 128 + chunk];
      __builtin_amdgcn_s_setprio(1);
#pragma unroll
      for (int st = 0; st < 4; st++)
#pragma unroll
        for (int it = 0; it < 4; it++)
          a2[st][it] = __builtin_amdgcn_mfma_f32_16x16x32_bf16(sv[st], axf[it][k0], a2[st][it], 0, 0, 0);
      __builtin_amdgcn_s_setprio(0);
    }
    {
      unsigned short* dst = ttp + ((size_t)(bh * 64 + c) << 14);
#pragma unroll
      for (int st = 0; st < 4; st++) {
        int l0 = (wc * 4 + st) * 16 + quad * 4;
#pragma unroll
        for (int it = 0; it < 4; it++) {
          int i = (wr * 4 + it) * 16 + l16;
          float f0 = a2[st][it][0], f1 = a2[st][it][1];
          float f2 = a2[st][it][2], f3 = a2[st][it][3];
          unsigned p0 = (unsigned)bf16r(f0) | ((unsigned)bf16r(f1) << 16);
          unsigned p1 = (unsigned)bf16r(f2) | ((unsigned)bf16r(f3) << 16);
          uint2 p; p.x = p0; p.y = p1;
          *(uint2*)(dst + (size_t)i * 128 + l0) = p;
          s[it] += (f0 + f1) + (f2 + f3);
          s2[it] += f0 * f0 + f1 * f1 + f2 * f2 + f3 * f3;
        }
      }
    }
  }
#pragma unroll
  for (int it = 0; it < 4; it++) {
    float v = s[it], v2 = s2[it];
    v += __shfl_xor(v, 16, 64);  v += __shfl_xor(v, 32, 64);
    v2 += __shfl_xor(v2, 16, 64); v2 += __shfl_xor(v2, 32, 64);
    if (quad == 0) {
      int i = (wr * 4 + it) * 16 + l16;
      atomicAdd(&sb[b * 128 + i], v);
      atomicAdd(&s2b[b * 128 + i], v2);
    }
  }
}

// ---- tail per (b,i): out[l][:] = gelu(instnorm(tt)[l,:] @ Wo1) @ Wo2 ----
// transpose staging widened: thread owns a row-PAIR (r0,r0+1) x 32-l quarter -> 4B ds writes
__global__ __launch_bounds__(256) void k_tail2(const unsigned short* __restrict__ ttp,
                                               const unsigned short* __restrict__ Wo1T,
                                               const unsigned short* __restrict__ Wo2T,
                                               float* __restrict__ out,
                                               const float* __restrict__ sb,
                                               const float* __restrict__ s2b,
                                               const float* __restrict__ sc) {
  int blk = blockIdx.x;   // 512
  int b = blk >> 7, i = blk & 127;
  __shared__ __align__(16) unsigned short As[16384];
  __shared__ __align__(16) unsigned short Bs[16384];
  int tid = threadIdx.x;
  int w = tid >> 6, lane = tid & 63, quad = lane >> 4, l16 = lane & 15;
  facc zf = {0.f, 0.f, 0.f, 0.f};
  facc a1[2][8];
#pragma unroll
  for (int a = 0; a < 2; a++)
#pragma unroll
    for (int bq = 0; bq < 8; bq++) a1[a][bq] = zf;
  for (int kc = 0; kc < 4; kc++) {
    if (kc) __syncthreads();
    {
      int rp = tid >> 2, qh = tid & 3;     // row pair rp -> rows 2rp,2rp+1; quarter qh -> l base qh*32
      int r0 = rp * 2, r1 = r0 + 1;
      int hc0 = kc * 128 + r0, hc1 = kc * 128 + r1;
      const unsigned short* s0 = ttp + (((size_t)(b * 8 + (hc0 >> 6)) * 64 + (hc0 & 63)) * 128 + i) * 128 + qh * 32;
      const unsigned short* s1 = ttp + (((size_t)(b * 8 + (hc1 >> 6)) * 64 + (hc1 & 63)) * 128 + i) * 128 + qh * 32;
#pragma unroll
      for (int q = 0; q < 4; q++) {
        uint4 v0 = *(const uint4*)(s0 + q * 8);
        uint4 v1 = *(const uint4*)(s1 + q * 8);
        unsigned short* p0 = (unsigned short*)&v0;
        unsigned short* p1 = (unsigned short*)&v1;
#pragma unroll
        for (int e = 0; e < 8; e++) {
          int l = qh * 32 + q * 8 + e;
          int idx = l * 128 + ((((r0 >> 3) ^ (l & 15)) << 3)) + (r0 & 7);
          *(unsigned*)&As[idx] = (unsigned)p0[e] | ((unsigned)p1[e] << 16);
        }
      }
      int r = tid >> 1, half = tid & 1;
      const unsigned short* sB = Wo1T + (size_t)r * 512 + kc * 128 + half * 64;
#pragma unroll
      for (int q = 0; q < 8; q++) {
        int c8 = half * 8 + q;
        *(uint4*)&Bs[r * 128 + ((c8 ^ (r & 15)) << 3)] = *(const uint4*)(sB + q * 8);
      }
    }
    __syncthreads();
#pragma unroll
    for (int k0 = 0; k0 < 4; k0++) {
      bfrag av[2];
#pragma unroll
      for (int it = 0; it < 2; it++) {
        int row = (w + it * 4) * 16 + l16;
        av[it] = *(const bfrag*)&As[row * 128 + (((k0 * 4 + quad) ^ l16) << 3)];
      }
#pragma unroll
      for (int nt = 0; nt < 8; nt++) {
        int row = nt * 16 + l16;
        bfrag bv = *(const bfrag*)&Bs[row * 128 + (((k0 * 4 + quad) ^ l16) << 3)];
        a1[0][nt] = __builtin_amdgcn_mfma_f32_16x16x32_bf16(av[0], bv, a1[0][nt], 0, 0, 0);
        a1[1][nt] = __builtin_amdgcn_mfma_f32_16x16x32_bf16(av[1], bv, a1[1][nt], 0, 0, 0);
      }
    }
  }
  float S = sb[b * 128 + i], S2 = s2b[b * 128 + i];
  float mean = S * (1.f / 65536.f);
  float var = S2 * (1.f / 65536.f) - mean * mean;
  float rs = rsqrtf(var + 1e-5f);
  __syncthreads();
#pragma unroll
  for (int it = 0; it < 2; it++)
#pragma unroll
    for (int nt = 0; nt < 8; nt++) {
      int n1 = nt * 16 + l16;
      float scn = sc[n1];
#pragma unroll
      for (int rr = 0; rr < 4; rr++) {
        int l = (w + it * 4) * 16 + quad * 4 + rr;
        float val = (a1[it][nt][rr] - mean * scn) * rs;
        As[l * 128 + (((n1 >> 3) ^ (l & 15)) << 3) + (n1 & 7)] = bf16r(gelu_f(val));
      }
    }
  {
    int r = tid >> 1, half = tid & 1;
    const unsigned short* sB = Wo2T + (size_t)r * 128 + half * 64;
#pragma unroll
    for (int q = 0; q < 8; q++) {
      int c8 = half * 8 + q;
      *(uint4*)&Bs[r * 128 + ((c8 ^ (r & 15)) << 3)] = *(const uint4*)(sB + q * 8);
    }
  }
  __syncthreads();
  facc a2[2][8];
#pragma unroll
  for (int a = 0; a < 2; a++)
#pragma unroll
    for (int bq = 0; bq < 8; bq++) a2[a][bq] = zf;
#pragma unroll
  for (int k0 = 0; k0 < 4; k0++) {
    bfrag av[2];
#pragma unroll
    for (int it = 0; it < 2; it++) {
      int row = (w + it * 4) * 16 + l16;
      av[it] = *(const bfrag*)&As[row * 128 + (((k0 * 4 + quad) ^ l16) << 3)];
    }
#pragma unroll
    for (int nt = 0; nt < 8; nt++) {
      int row = nt * 16 + l16;
      bfrag bv = *(const bfrag*)&Bs[row * 128 + (((k0 * 4 + quad) ^ l16) << 3)];
      a2[0][nt] = __builtin_amdgcn_mfma_f32_16x16x32_bf16(av[0], bv, a2[0][nt], 0, 0, 0);
      a2[1][nt] = __builtin_amdgcn_mfma_f32_16x16x32_bf16(av[1], bv, a2[1][nt], 0, 0, 0);
    }
  }
#pragma unroll
  for (int it = 0; it < 2; it++)
#pragma unroll
    for (int nt = 0; nt < 8; nt++) {
      int n2 = nt * 16 + l16;
#pragma unroll
      for (int rr = 0; rr < 4; rr++) {
        int l = (w + it * 4) * 16 + quad * 4 + rr;
        out[((size_t)(b * 16384 + i * 128 + l)) * 128 + n2] = a2[it][nt][rr];
      }
    }
}

extern "C" void kernel_launch(void* const* d_in, const int* in_sizes, int n_in,
                              void* d_out, int out_size, void* d_ws, size_t ws_size,
                              hipStream_t stream) {
  const float* u = (const float*)d_in[0];
  const float* pos_x = (const float*)d_in[1];
  const float* pos_y = (const float*)d_in[2];
  const float* ln_g = (const float*)d_in[3];
  const float* ln_b = (const float*)d_in[4];
  const float* Wv = (const float*)d_in[5];
  const float* Win = (const float*)d_in[6];
  const float* px_Win = (const float*)d_in[7];
  const float* px_g = (const float*)d_in[8];
  const float* px_b = (const float*)d_in[9];
  const float* px_W1 = (const float*)d_in[10];
  const float* px_b1 = (const float*)d_in[11];
  const float* px_W2 = (const float*)d_in[12];
  const float* px_b2 = (const float*)d_in[13];
  const float* py_Win = (const float*)d_in[14];
  const float* py_g = (const float*)d_in[15];
  const float* py_b = (const float*)d_in[16];
  const float* py_W1 = (const float*)d_in[17];
  const float* py_b1 = (const float*)d_in[18];
  const float* py_W2 = (const float*)d_in[19];
  const float* py_b2 = (const float*)d_in[20];
  const float* Wqk_x = (const float*)d_in[21];
  const float* Wqk_y = (const float*)d_in[22];
  const float* Wo1 = (const float*)d_in[23];
  const float* Wo2 = (const float*)d_in[24];
  float* out = (float*)d_out;

  const size_t NEED = 44868736;  // floats (~180 MB); harness ws is 256 MiB
  if (ws_size < NEED * sizeof(float)) return;
  float* ws = (float*)d_ws;
  unsigned short* un_bf = (unsigned short*)ws;               // [65536][128]
  unsigned short* vT    = (unsigned short*)(ws + 4194304);   // [512][65536]
  unsigned short* ttp   = (unsigned short*)(ws + 20971520);  // [32][64][128][128]
  float* small = ws + 37748736;
  float* Wcx   = small + 131072;        // 16384
  float* Wcy   = small + 147456;        // 16384
  float* ux    = small + 163840;        // 32768
  float* uy    = small + 196608;        // 32768
  float* qkx   = small + 229376;        // 1572864
  float* qky   = small + 1802240;       // 1572864
  float* tabx  = small + 3375104;       // 24576 (128*96 float2)
  float* taby  = small + 3399680;       // 24576
  unsigned short* kx_bf = (unsigned short*)(small + 6520832);  // 524288 el
  unsigned short* ky_bf = (unsigned short*)(small + 6782976);  // 524288 el
  unsigned short* WvT   = (unsigned short*)(small + 7045120);  // 65536 el
  unsigned short* Wo1T  = (unsigned short*)(small + 7077888);  // 65536 el
  unsigned short* Wo2T  = (unsigned short*)(small + 7110656);  // 16384 el
  float* sbuf  = small + 7118848;       // 512 (+512 s2buf, contiguous)
  float* s2buf = small + 7119360;       // 512
  float* scol  = small + 7119872;       // 128

  // Phase A (4 launches; memset folded into k_lnw)
  k_lnw<<<17066, 256, 0, stream>>>(u, ln_g, ln_b, un_bf, Wv, Wo1, Wo2,
                                   WvT, Wo1T, Wo2T, scol,
                                   Win, px_Win, py_Win, Wcx, Wcy,
                                   pos_x, pos_y, tabx, taby, sbuf);
  k_pvt<<<1024, 256, 0, stream>>>(WvT, un_bf, vT,
                                  Wcx, Wcy, px_g, py_g, px_b, py_b,
                                  px_W1, py_W1, px_b1, py_b1, px_W2, py_W2,
                                  px_b2, py_b2, ux, uy);
  k_gemmz<<<dim3(48, 8, 2), 256, 0, stream>>>(ux, Wqk_x, qkx, uy, Wqk_y, qky,
                                              64, 64, 3072, 3072);
  k_qkt2<<<dim3(2, 2, 64), 512, 0, stream>>>(qkx, qky, tabx, taby, kx_bf, ky_bf);

  // Phase B (2 launches)
  k_fuse12<<<512, 256, 0, stream>>>(kx_bf, ky_bf, vT, ttp, sbuf, s2buf);
  k_tail2<<<512, 256, 0, stream>>>(ttp, Wo1T, Wo2T, out, sbuf, s2buf, scol);
}

// Round 11
// 283.736 us; speedup vs baseline: 1.0700x; 1.0700x over previous
//
#include <hip/hip_runtime.h>
#include <math.h>

#define KDD 192

typedef __attribute__((ext_vector_type(8))) short bfrag;   // 8 bf16
typedef __attribute__((ext_vector_type(4))) float facc;    // 4 fp32

__device__ inline unsigned short bf16r(float x) {
  union { float f; unsigned u; } v; v.f = x;
  unsigned r = v.u + 0x7fffu + ((v.u >> 16) & 1u);
  return (unsigned short)(r >> 16);
}
__device__ inline float bf2f(unsigned short h) {
  union { unsigned u; float f; } v; v.u = ((unsigned)h) << 16; return v.f;
}
__device__ inline float gelu_f(float x) {
  return x * 0.5f * (1.f + erff(x * 0.70710678f));
}
// async global->LDS, 16B per lane; LDS dest = wave-uniform base + lane*16
__device__ __forceinline__ void gload16(const void* g, void* l) {
  __builtin_amdgcn_global_load_lds((const __attribute__((address_space(1))) unsigned int*)g,
                                   (__attribute__((address_space(3))) unsigned int*)l,
                                   16, 0, 0);
}

// ---------------- mega phase-A kernel: LN + weight-prep + Wc GEMM + RoPE tables + stat-zero ----
__global__ __launch_bounds__(256) void k_lnw(const float* __restrict__ x,
                                             const float* __restrict__ g,
                                             const float* __restrict__ bb,
                                             unsigned short* __restrict__ y,
                                             const float* __restrict__ Wv,
                                             const float* __restrict__ Wo1,
                                             const float* __restrict__ Wo2,
                                             unsigned short* __restrict__ WvT,
                                             unsigned short* __restrict__ Wo1T,
                                             unsigned short* __restrict__ Wo2T,
                                             float* __restrict__ scol,
                                             const float* __restrict__ Win,
                                             const float* __restrict__ pxW,
                                             const float* __restrict__ pyW,
                                             float* __restrict__ Wcx,
                                             float* __restrict__ Wcy,
                                             const float* __restrict__ pos_x,
                                             const float* __restrict__ pos_y,
                                             float* __restrict__ tabx,
                                             float* __restrict__ taby,
                                             float* __restrict__ sbuf) {
  __shared__ float As[16][64];
  __shared__ float Bs[16][64];
  int bid = blockIdx.x, t = threadIdx.x;
  if (bid < 16384) {
    int w = t >> 6, lane = t & 63;
    size_t row = (size_t)bid * 4 + w;
    float2 v = *(const float2*)(x + row * 128 + lane * 2);
    float s = v.x + v.y, s2 = v.x * v.x + v.y * v.y;
#pragma unroll
    for (int off = 1; off < 64; off <<= 1) {
      s += __shfl_xor(s, off, 64);
      s2 += __shfl_xor(s2, off, 64);
    }
    float mean = s * (1.f / 128.f);
    float var = s2 * (1.f / 128.f) - mean * mean;
    float r = rsqrtf(var + 1e-5f);
    float2 gg = *(const float2*)(g + lane * 2);
    float2 bv = *(const float2*)(bb + lane * 2);
    unsigned h0 = bf16r((v.x - mean) * r * gg.x + bv.x);
    unsigned h1 = bf16r((v.y - mean) * r * gg.y + bv.y);
    *(unsigned*)(y + row * 128 + lane * 2) = h0 | (h1 << 16);
    return;
  }
  if (bid < 16961) {
    int blk = bid - 16384;
    if (blk < 256) {
      int idx = blk * 256 + t;            // 65536: WvT[hc][d] = Wv[d][hc]
      int c = idx >> 7, r = idx & 127;
      WvT[(size_t)c * 128 + r] = bf16r(Wv[(size_t)r * 512 + c]);
    } else if (blk < 512) {
      int idx = (blk - 256) * 256 + t;    // 65536: Wo1T[n][k] = Wo1[k][n]
      int n = idx >> 9, k = idx & 511;
      Wo1T[(size_t)n * 512 + k] = bf16r(Wo1[(size_t)k * 128 + n]);
    } else if (blk < 576) {
      int idx = (blk - 512) * 256 + t;    // 16384: Wo2T[n][k] = Wo2[k][n]
      int n = idx >> 7, k = idx & 127;
      Wo2T[n * 128 + k] = bf16r(Wo2[k * 128 + n]);
    } else {
      if (t < 128) {
        float a = 0;
        for (int k = 0; k < 512; k++) a += bf2f(bf16r(Wo1[k * 128 + t]));
        scol[t] = a;
      }
    }
    return;
  }
  if (bid < 16969) {
    int idx = bid - 16961;                 // 0..7
    int n0 = (idx & 1) * 64, m0 = ((idx >> 1) & 1) * 64;
    const float* A = Win;
    const float* Bm = (idx >> 2) ? pyW : pxW;
    float* C = (idx >> 2) ? Wcy : Wcx;
    int tx = t & 15, ty = t >> 4;
    float acc[4][4] = {};
    int la_m = t >> 2, la_k = (t & 3) * 4;
    int lb_k = t >> 4, lb_n = (t & 15) * 4;
    for (int k0 = 0; k0 < 128; k0 += 16) {
      float4 a4 = *(const float4*)(A + (size_t)(m0 + la_m) * 128 + k0 + la_k);
      As[la_k + 0][la_m] = a4.x; As[la_k + 1][la_m] = a4.y;
      As[la_k + 2][la_m] = a4.z; As[la_k + 3][la_m] = a4.w;
      float4 b4 = *(const float4*)(Bm + (size_t)(k0 + lb_k) * 128 + n0 + lb_n);
      *(float4*)&Bs[lb_k][lb_n] = b4;
      __syncthreads();
#pragma unroll
      for (int kk = 0; kk < 16; kk++) {
        float4 av = *(const float4*)&As[kk][ty * 4];
        float4 bv = *(const float4*)&Bs[kk][tx * 4];
        float a[4] = {av.x, av.y, av.z, av.w};
        float b[4] = {bv.x, bv.y, bv.z, bv.w};
#pragma unroll
        for (int i = 0; i < 4; i++)
#pragma unroll
          for (int j = 0; j < 4; j++) acc[i][j] += a[i] * b[j];
      }
      __syncthreads();
    }
#pragma unroll
    for (int i = 0; i < 4; i++) {
      float4 o;
      o.x = acc[i][0]; o.y = acc[i][1]; o.z = acc[i][2]; o.w = acc[i][3];
      *(float4*)(C + (size_t)(m0 + ty * 4 + i) * 128 + n0 + tx * 4) = o;
    }
    return;
  }
  if (bid < 17065) {
    int id = (bid - 16969) * 256 + t;      // 0..24575
    int axis = id >= 12288;
    int rem = axis ? id - 12288 : id;
    int n = rem / 96, fi = rem - n * 96;
    const float* pos = axis ? pos_y : pos_x;
    float inv = expf(-logf(10000.f) * ((float)fi / 96.f));
    float f = pos[n] * 64.f * inv;
    float2 cssn;
    cssn.x = cosf(f);
    cssn.y = sinf(f);
    ((float2*)(axis ? taby : tabx))[n * 96 + fi] = cssn;
    return;
  }
  {
    float4 z4 = {0.f, 0.f, 0.f, 0.f};
    ((float4*)sbuf)[t] = z4;               // 256 * 16B = 1024 floats (sbuf+s2buf)
  }
}

// ---------------- merged vt + pooling-MLP launch ----------------
// blocks [0,512): vt (un tile staged once, 4 mt per block)
// blocks [512,1024): pool2, 2 (sel,row) units per 256-thr block (R8 simple loops).
// SINGLE 32KB shared buffer, branch-aliased (branches never coexist) -> LDS = 32768
// exactly -> 5 blocks/CU instead of 4.
__global__ __launch_bounds__(256) void k_pvt(const unsigned short* __restrict__ WvT,
                                             const unsigned short* __restrict__ un,
                                             unsigned short* __restrict__ vT,
                                             const float* __restrict__ Wc0, const float* __restrict__ Wc1,
                                             const float* __restrict__ g0, const float* __restrict__ g1,
                                             const float* __restrict__ bb0, const float* __restrict__ bb1,
                                             const float* __restrict__ W10, const float* __restrict__ W11,
                                             const float* __restrict__ b10, const float* __restrict__ b11,
                                             const float* __restrict__ W20, const float* __restrict__ W21,
                                             const float* __restrict__ b20, const float* __restrict__ b21,
                                             float* __restrict__ o0, float* __restrict__ o1) {
  __shared__ __align__(16) unsigned char smem[32768];
  int bid = blockIdx.x;
  int tid = threadIdx.x;
  if (bid < 512) {
    // ---- vt ----
    unsigned short* Bs = (unsigned short*)smem;
    int nt = bid;
    int w = tid >> 6, lane = tid & 63, quad = lane >> 4, l16 = lane & 15;
    int wr = w >> 1, wc = w & 1;
    {
      const unsigned short* sbp = un + (size_t)nt * 16384;
#pragma unroll
      for (int q = 0; q < 8; q++) {
        int rbase = w * 32 + q * 4;
        int r = rbase + quad;
        gload16(sbp + (size_t)r * 128 + ((l16 ^ (r & 15)) << 3), &Bs[rbase * 128]);
      }
    }
    __syncthreads();
    facc zf = {0.f, 0.f, 0.f, 0.f};
#pragma unroll
    for (int mt = 0; mt < 4; mt++) {
      const unsigned short* ap = WvT + (size_t)mt * 128 * 128;
      facc acc[4][4];
#pragma unroll
      for (int lt = 0; lt < 4; lt++)
#pragma unroll
        for (int xt = 0; xt < 4; xt++) acc[lt][xt] = zf;
#pragma unroll
      for (int k0 = 0; k0 < 4; k0++) {
        int chunk = ((k0 * 4 + quad) ^ l16) << 3;
        bfrag bv[4], av[4];
#pragma unroll
        for (int lt = 0; lt < 4; lt++)
          bv[lt] = *(const bfrag*)&Bs[((wc * 4 + lt) * 16 + l16) * 128 + chunk];
#pragma unroll
        for (int xt = 0; xt < 4; xt++)
          av[xt] = *(const bfrag*)(ap + (size_t)((wr * 4 + xt) * 16 + l16) * 128 + k0 * 32 + quad * 8);
        __builtin_amdgcn_s_setprio(1);
#pragma unroll
        for (int lt = 0; lt < 4; lt++)
#pragma unroll
          for (int xt = 0; xt < 4; xt++)
            acc[lt][xt] = __builtin_amdgcn_mfma_f32_16x16x32_bf16(bv[lt], av[xt], acc[lt][xt], 0, 0, 0);
        __builtin_amdgcn_s_setprio(0);
      }
#pragma unroll
      for (int xt = 0; xt < 4; xt++) {
        int hc = mt * 128 + (wr * 4 + xt) * 16 + l16;
        unsigned short* dst = vT + (size_t)hc * 65536 + nt * 128 + quad * 4;
#pragma unroll
        for (int lt = 0; lt < 4; lt++) {
          facc a = acc[lt][xt];
          uint2 p;
          p.x = (unsigned)bf16r(a[0]) | ((unsigned)bf16r(a[1]) << 16);
          p.y = (unsigned)bf16r(a[2]) | ((unsigned)bf16r(a[3]) << 16);
          *(uint2*)(dst + (wc * 4 + lt) * 16) = p;
        }
      }
    }
    return;
  }
  // ---- pool2: 2 units per block (aliased scratch inside smem) ----
  float* xin = (float*)smem;          // [2][128]
  float* h1  = (float*)smem + 256;    // [2][128]
  float* h3  = (float*)smem + 512;    // [2][128]
  float* ps  = (float*)smem + 768;    // [2][2]
  float* ps2 = (float*)smem + 772;    // [2][2]
  int u2 = tid >> 7;                  // sub-unit 0/1
  int t = tid & 127;
  int unit = (bid - 512) * 2 + u2;    // 0..1023
  int sel = unit >> 9, row = unit & 511;
  const float* Wc = sel ? Wc1 : Wc0;
  const float* g = sel ? g1 : g0;     const float* bb = sel ? bb1 : bb0;
  const float* W1 = sel ? W11 : W10;  const float* b1 = sel ? b11 : b10;
  const float* W2 = sel ? W21 : W20;  const float* b2 = sel ? b21 : b20;
  float* out = sel ? o1 : o0;
  // fused k_means: mean over the reduced axis, identical summation order
  {
    float s0 = 0.f;
    if (sel == 0) {
      const unsigned short* p = un + (size_t)row * 16384 + t;
      for (int j = 0; j < 128; j++) s0 += bf2f(p[(size_t)j * 128]);
    } else {
      int b = row >> 7, j = row & 127;
      const unsigned short* p = un + (size_t)b * 2097152 + (size_t)j * 128 + t;
      for (int i = 0; i < 128; i++) s0 += bf2f(p[(size_t)i * 16384]);
    }
    xin[u2 * 128 + t] = s0 * (1.f / 128.f);
  }
  __syncthreads();
  float a = 0;
  for (int k = 0; k < 128; k++) a += xin[u2 * 128 + k] * Wc[k * 128 + t];
  float s = a, s2 = a * a;
  for (int off = 32; off > 0; off >>= 1) {
    s += __shfl_down(s, off, 64);
    s2 += __shfl_down(s2, off, 64);
  }
  if ((t & 63) == 0) { ps[u2 * 2 + (t >> 6)] = s; ps2[u2 * 2 + (t >> 6)] = s2; }
  __syncthreads();
  float S = ps[u2 * 2] + ps[u2 * 2 + 1], S2 = ps2[u2 * 2] + ps2[u2 * 2 + 1];
  float mean = S * (1.f / 128.f);
  float var = S2 * (1.f / 128.f) - mean * mean;
  float r = rsqrtf(var + 1e-5f);
  h1[u2 * 128 + t] = (a - mean) * r * g[t] + bb[t];
  __syncthreads();
  float u1 = b1[t], uu2 = b1[t + 128];
  for (int k = 0; k < 128; k++) {
    float hv = h1[u2 * 128 + k];
    u1 += hv * W1[k * 256 + t];
    uu2 += hv * W1[k * 256 + t + 128];
  }
  h3[u2 * 128 + t] = gelu_f(u1) * uu2;
  __syncthreads();
  if (t < 64) {
    float o = b2[t];
    for (int k = 0; k < 128; k++) o += h3[u2 * 128 + k] * W2[k * 64 + t];
    out[(size_t)row * 64 + t] = o;
  }
}

// ---------------- fp32 GEMM, z-batched (qk projection) ----------------
__global__ __launch_bounds__(256) void k_gemmz(const float* __restrict__ A0,
                                               const float* __restrict__ B0,
                                               float* __restrict__ C0,
                                               const float* __restrict__ A1,
                                               const float* __restrict__ B1,
                                               float* __restrict__ C1,
                                               int K, int lda, int ldb, int ldc) {
  const float* A = blockIdx.z ? A1 : A0;
  const float* Bm = blockIdx.z ? B1 : B0;
  float* C = blockIdx.z ? C1 : C0;
  __shared__ float As[16][64];
  __shared__ float Bs[16][64];
  int tid = threadIdx.x;
  int n0 = blockIdx.x * 64, m0 = blockIdx.y * 64;
  int tx = tid & 15, ty = tid >> 4;
  float acc[4][4] = {};
  int la_m = tid >> 2, la_k = (tid & 3) * 4;
  int lb_k = tid >> 4, lb_n = (tid & 15) * 4;
  for (int k0 = 0; k0 < K; k0 += 16) {
    float4 a4 = *(const float4*)(A + (size_t)(m0 + la_m) * lda + k0 + la_k);
    As[la_k + 0][la_m] = a4.x; As[la_k + 1][la_m] = a4.y;
    As[la_k + 2][la_m] = a4.z; As[la_k + 3][la_m] = a4.w;
    float4 b4 = *(const float4*)(Bm + (size_t)(k0 + lb_k) * ldb + n0 + lb_n);
    *(float4*)&Bs[lb_k][lb_n] = b4;
    __syncthreads();
#pragma unroll
    for (int kk = 0; kk < 16; kk++) {
      float4 av = *(const float4*)&As[kk][ty * 4];
      float4 bv = *(const float4*)&Bs[kk][tx * 4];
      float a[4] = {av.x, av.y, av.z, av.w};
      float b[4] = {bv.x, bv.y, bv.z, bv.w};
#pragma unroll
      for (int i = 0; i < 4; i++)
#pragma unroll
        for (int j = 0; j < 4; j++) acc[i][j] += a[i] * b[j];
    }
    __syncthreads();
  }
#pragma unroll
  for (int i = 0; i < 4; i++) {
    float4 o;
    o.x = acc[i][0]; o.y = acc[i][1]; o.z = acc[i][2]; o.w = acc[i][3];
    *(float4*)(C + (size_t)(m0 + ty * 4 + i) * ldc + n0 + tx * 4) = o;
  }
}

// ---------------- batched Q@K^T with fused rotary staging, z-batched x/y ----------------
__global__ __launch_bounds__(512) void k_qkt2(const float* __restrict__ qk0, const float* __restrict__ qk1,
                                              const float* __restrict__ tab0, const float* __restrict__ tab1,
                                              unsigned short* __restrict__ C0,
                                              unsigned short* __restrict__ C1) {
  int z = blockIdx.z;
  int bh = z & 31;
  int b = bh >> 3, h = bh & 7;
  const float* qk = (z < 32) ? qk0 : qk1;
  const float* tab = (z < 32) ? tab0 : tab1;
  unsigned short* Cb = ((z < 32) ? C0 : C1) + (size_t)bh * 16384;
  __shared__ float As[16][64];
  __shared__ float Bs[16][64];
  int tid = threadIdx.x;
  int i0 = blockIdx.y * 64, j0 = blockIdx.x * 64;
  int tx = tid & 15, ty = tid >> 4;
  float acc[2][4] = {};
  int l_m = tid >> 3, l_k = (tid & 7) * 2;
  for (int k0 = 0; k0 < KDD; k0 += 16) {
    int d = k0 + l_k;                    // even, 0..190
    int fi = d < 96 ? d : d - 96;
    float sgn = d < 96 ? -1.f : 1.f;
    int prt = d < 96 ? d + 96 : d - 96;
    {
      int n = i0 + l_m;
      const float* src = qk + (size_t)(b * 128 + n) * 3072 + h * 192;
      float2 qd = *(const float2*)(src + d);
      float2 qp = *(const float2*)(src + prt);
      float2 t0 = *(const float2*)(tab + (size_t)(n * 96 + fi) * 2);
      float2 t1 = *(const float2*)(tab + (size_t)(n * 96 + fi + 1) * 2);
      As[l_k + 0][l_m] = qd.x * t0.x + sgn * qp.x * t0.y;
      As[l_k + 1][l_m] = qd.y * t1.x + sgn * qp.y * t1.y;
    }
    {
      int n = j0 + l_m;
      const float* src = qk + (size_t)(b * 128 + n) * 3072 + 1536 + h * 192;
      float2 qd = *(const float2*)(src + d);
      float2 qp = *(const float2*)(src + prt);
      float2 t0 = *(const float2*)(tab + (size_t)(n * 96 + fi) * 2);
      float2 t1 = *(const float2*)(tab + (size_t)(n * 96 + fi + 1) * 2);
      Bs[l_k + 0][l_m] = qd.x * t0.x + sgn * qp.x * t0.y;
      Bs[l_k + 1][l_m] = qd.y * t1.x + sgn * qp.y * t1.y;
    }
    __syncthreads();
#pragma unroll
    for (int kk = 0; kk < 16; kk++) {
      float2 av = *(const float2*)&As[kk][ty * 2];
      float4 bv = *(const float4*)&Bs[kk][tx * 4];
      float a[2] = {av.x, av.y};
      float b2[4] = {bv.x, bv.y, bv.z, bv.w};
#pragma unroll
      for (int i = 0; i < 2; i++)
#pragma unroll
        for (int j = 0; j < 4; j++) acc[i][j] += a[i] * b2[j];
    }
    __syncthreads();
  }
#pragma unroll
  for (int i = 0; i < 2; i++) {
    unsigned h0 = bf16r(acc[i][0]), h1 = bf16r(acc[i][1]);
    unsigned h2 = bf16r(acc[i][2]), h3 = bf16r(acc[i][3]);
    uint2 pk;
    pk.x = h0 | (h1 << 16);
    pk.y = h2 | (h3 << 16);
    *(uint2*)(Cb + (size_t)(i0 + ty * 2 + i) * 128 + j0 + tx * 4) = pk;
  }
}

// ==== xor-swizzled LDS helpers: logical (row 0..127, col 0..127) on a 128x128 ushort tile ====
// phys = row*128 + ((c8 ^ (row&15))<<3) + (col&7), c8 = col>>3

// ---- fused x/y attend per (bh, 4-c strip): tt'[bh][c][i][l] = kx @ (Vc @ ky^T), + stats ----
// (R1-benched version: Ky staged once in LDS, V via gload_lds at loop top — ~41 us)
__global__ __launch_bounds__(256, 2) void k_fuse12(const unsigned short* __restrict__ kxall,
                                                   const unsigned short* __restrict__ kyall,
                                                   const unsigned short* __restrict__ vT,
                                                   unsigned short* __restrict__ ttp,
                                                   float* __restrict__ sb,
                                                   float* __restrict__ s2b) {
  int blk = blockIdx.x;            // 512
  int bh = blk >> 4, strip = blk & 15;
  int b = bh >> 3, h = bh & 7;
  __shared__ __align__(16) unsigned short Ky[16384];
  __shared__ __align__(16) unsigned short Vs[16384];
  int tid = threadIdx.x;
  int w = tid >> 6, lane = tid & 63, quad = lane >> 4, l16 = lane & 15;
  int wr = w >> 1, wc = w & 1;

  {
    const unsigned short* kb = kyall + (size_t)bh * 16384;
#pragma unroll
    for (int q = 0; q < 8; q++) {
      int rbase = w * 32 + q * 4;
      int r = rbase + quad;
      gload16(kb + (size_t)r * 128 + ((l16 ^ (r & 15)) << 3), &Ky[rbase * 128]);
    }
  }
  bfrag axf[4][4];
  {
    const unsigned short* xb = kxall + (size_t)bh * 16384;
#pragma unroll
    for (int it = 0; it < 4; it++) {
      int i = (wr * 4 + it) * 16 + l16;
#pragma unroll
      for (int k0 = 0; k0 < 4; k0++)
        axf[it][k0] = *(const bfrag*)(xb + (size_t)i * 128 + k0 * 32 + quad * 8);
    }
  }

  float s[4] = {0.f, 0.f, 0.f, 0.f}, s2[4] = {0.f, 0.f, 0.f, 0.f};
  facc zf = {0.f, 0.f, 0.f, 0.f};

  for (int cc = 0; cc < 4; cc++) {
    int c = strip * 4 + cc;
    if (cc) __syncthreads();
    {
      const unsigned short* vb = vT + (size_t)(h * 64 + c) * 65536 + (size_t)b * 16384;
#pragma unroll
      for (int q = 0; q < 8; q++) {
        int rbase = w * 32 + q * 4;
        int r = rbase + quad;
        gload16(vb + (size_t)r * 128 + ((l16 ^ (r & 15)) << 3), &Vs[rbase * 128]);
      }
    }
    __syncthreads();

    facc a1[4][4];
#pragma unroll
    for (int xt = 0; xt < 4; xt++)
#pragma unroll
      for (int lt = 0; lt < 4; lt++) a1[xt][lt] = zf;
#pragma unroll
    for (int k0 = 0; k0 < 4; k0++) {
      int chunk = ((k0 * 4 + quad) ^ l16) << 3;
      bfrag av[4], bv[4];
#pragma unroll
      for (int xt = 0; xt < 4; xt++)
        av[xt] = *(const bfrag*)&Vs[((wr * 4 + xt) * 16 + l16) * 128 + chunk];
#pragma unroll
      for (int lt = 0; lt < 4; lt++)
        bv[lt] = *(const bfrag*)&Ky[((wc * 4 + lt) * 16 + l16) * 128 + chunk];
      __builtin_amdgcn_s_setprio(1);
#pragma unroll
      for (int xt = 0; xt < 4; xt++)
#pragma unroll
        for (int lt = 0; lt < 4; lt++)
          a1[xt][lt] = __builtin_amdgcn_mfma_f32_16x16x32_bf16(av[xt], bv[lt], a1[xt][lt], 0, 0, 0);
      __builtin_amdgcn_s_setprio(0);
    }
    __syncthreads();
#pragma unroll
    for (int xt = 0; xt < 4; xt++) {
      int xc = (wr * 4 + xt) * 2 + (quad >> 1);
      int xo = (quad & 1) * 4;
#pragma unroll
      for (int lt = 0; lt < 4; lt++) {
        int l = (wc * 4 + lt) * 16 + l16;
        unsigned p0 = (unsigned)bf16r(a1[xt][lt][0]) | ((unsigned)bf16r(a1[xt][lt][1]) << 16);
        unsigned p1 = (unsigned)bf16r(a1[xt][lt][2]) | ((unsigned)bf16r(a1[xt][lt][3]) << 16);
        uint2 p; p.x = p0; p.y = p1;
        *(uint2*)&Vs[l * 128 + ((xc ^ (l & 15)) << 3) + xo] = p;
      }
    }
    __syncthreads();

    facc a2[4][4];
#pragma unroll
    for (int st = 0; st < 4; st++)
#pragma unroll
      for (int it = 0; it < 4; it++) a2[st][it] = zf;
#pragma unroll
    for (int k0 = 0; k0 < 4; k0++) {
      int chunk = ((k0 * 4 + quad) ^ l16) << 3;
      bfrag sv[4];
#pragma unroll
      for (int st = 0; st < 4; st++)
        sv[st] = *(const bfrag*)&Vs[((wc * 4 + st) * 16 + l16) * 128 + chunk];
      __builtin_amdgcn_s_setprio(1);
#pragma unroll
      for (int st = 0; st < 4; st++)
#pragma unroll
        for (int it = 0; it < 4; it++)
          a2[st][it] = __builtin_amdgcn_mfma_f32_16x16x32_bf16(sv[st], axf[it][k0], a2[st][it], 0, 0, 0);
      __builtin_amdgcn_s_setprio(0);
    }
    {
      unsigned short* dst = ttp + ((size_t)(bh * 64 + c) << 14);
#pragma unroll
      for (int st = 0; st < 4; st++) {
        int l0 = (wc * 4 + st) * 16 + quad * 4;
#pragma unroll
        for (int it = 0; it < 4; it++) {
          int i = (wr * 4 + it) * 16 + l16;
          float f0 = a2[st][it][0], f1 = a2[st][it][1];
          float f2 = a2[st][it][2], f3 = a2[st][it][3];
          unsigned p0 = (unsigned)bf16r(f0) | ((unsigned)bf16r(f1) << 16);
          unsigned p1 = (unsigned)bf16r(f2) | ((unsigned)bf16r(f3) << 16);
          uint2 p; p.x = p0; p.y = p1;
          *(uint2*)(dst + (size_t)i * 128 + l0) = p;
          s[it] += (f0 + f1) + (f2 + f3);
          s2[it] += f0 * f0 + f1 * f1 + f2 * f2 + f3 * f3;
        }
      }
    }
  }
#pragma unroll
  for (int it = 0; it < 4; it++) {
    float v = s[it], v2 = s2[it];
    v += __shfl_xor(v, 16, 64);  v += __shfl_xor(v, 32, 64);
    v2 += __shfl_xor(v2, 16, 64); v2 += __shfl_xor(v2, 32, 64);
    if (quad == 0) {
      int i = (wr * 4 + it) * 16 + l16;
      atomicAdd(&sb[b * 128 + i], v);
      atomicAdd(&s2b[b * 128 + i], v2);
    }
  }
}

// ---- tail per (b,i): out[l][:] = gelu(instnorm(tt)[l,:] @ Wo1) @ Wo2 ----
// transpose staging widened: thread owns a row-PAIR (r0,r0+1) x 32-l quarter -> 4B ds writes
__global__ __launch_bounds__(256) void k_tail2(const unsigned short* __restrict__ ttp,
                                               const unsigned short* __restrict__ Wo1T,
                                               const unsigned short* __restrict__ Wo2T,
                                               float* __restrict__ out,
                                               const float* __restrict__ sb,
                                               const float* __restrict__ s2b,
                                               const float* __restrict__ sc) {
  int blk = blockIdx.x;   // 512
  int b = blk >> 7, i = blk & 127;
  __shared__ __align__(16) unsigned short As[16384];
  __shared__ __align__(16) unsigned short Bs[16384];
  int tid = threadIdx.x;
  int w = tid >> 6, lane = tid & 63, quad = lane >> 4, l16 = lane & 15;
  facc zf = {0.f, 0.f, 0.f, 0.f};
  facc a1[2][8];
#pragma unroll
  for (int a = 0; a < 2; a++)
#pragma unroll
    for (int bq = 0; bq < 8; bq++) a1[a][bq] = zf;
  for (int kc = 0; kc < 4; kc++) {
    if (kc) __syncthreads();
    {
      int rp = tid >> 2, qh = tid & 3;     // row pair rp -> rows 2rp,2rp+1; quarter qh -> l base qh*32
      int r0 = rp * 2, r1 = r0 + 1;
      int hc0 = kc * 128 + r0, hc1 = kc * 128 + r1;
      const unsigned short* s0 = ttp + (((size_t)(b * 8 + (hc0 >> 6)) * 64 + (hc0 & 63)) * 128 + i) * 128 + qh * 32;
      const unsigned short* s1 = ttp + (((size_t)(b * 8 + (hc1 >> 6)) * 64 + (hc1 & 63)) * 128 + i) * 128 + qh * 32;
#pragma unroll
      for (int q = 0; q < 4; q++) {
        uint4 v0 = *(const uint4*)(s0 + q * 8);
        uint4 v1 = *(const uint4*)(s1 + q * 8);
        unsigned short* p0 = (unsigned short*)&v0;
        unsigned short* p1 = (unsigned short*)&v1;
#pragma unroll
        for (int e = 0; e < 8; e++) {
          int l = qh * 32 + q * 8 + e;
          int idx = l * 128 + ((((r0 >> 3) ^ (l & 15)) << 3)) + (r0 & 7);
          *(unsigned*)&As[idx] = (unsigned)p0[e] | ((unsigned)p1[e] << 16);
        }
      }
      int r = tid >> 1, half = tid & 1;
      const unsigned short* sB = Wo1T + (size_t)r * 512 + kc * 128 + half * 64;
#pragma unroll
      for (int q = 0; q < 8; q++) {
        int c8 = half * 8 + q;
        *(uint4*)&Bs[r * 128 + ((c8 ^ (r & 15)) << 3)] = *(const uint4*)(sB + q * 8);
      }
    }
    __syncthreads();
#pragma unroll
    for (int k0 = 0; k0 < 4; k0++) {
      bfrag av[2];
#pragma unroll
      for (int it = 0; it < 2; it++) {
        int row = (w + it * 4) * 16 + l16;
        av[it] = *(const bfrag*)&As[row * 128 + (((k0 * 4 + quad) ^ l16) << 3)];
      }
#pragma unroll
      for (int nt = 0; nt < 8; nt++) {
        int row = nt * 16 + l16;
        bfrag bv = *(const bfrag*)&Bs[row * 128 + (((k0 * 4 + quad) ^ l16) << 3)];
        a1[0][nt] = __builtin_amdgcn_mfma_f32_16x16x32_bf16(av[0], bv, a1[0][nt], 0, 0, 0);
        a1[1][nt] = __builtin_amdgcn_mfma_f32_16x16x32_bf16(av[1], bv, a1[1][nt], 0, 0, 0);
      }
    }
  }
  float S = sb[b * 128 + i], S2 = s2b[b * 128 + i];
  float mean = S * (1.f / 65536.f);
  float var = S2 * (1.f / 65536.f) - mean * mean;
  float rs = rsqrtf(var + 1e-5f);
  __syncthreads();
#pragma unroll
  for (int it = 0; it < 2; it++)
#pragma unroll
    for (int nt = 0; nt < 8; nt++) {
      int n1 = nt * 16 + l16;
      float scn = sc[n1];
#pragma unroll
      for (int rr = 0; rr < 4; rr++) {
        int l = (w + it * 4) * 16 + quad * 4 + rr;
        float val = (a1[it][nt][rr] - mean * scn) * rs;
        As[l * 128 + (((n1 >> 3) ^ (l & 15)) << 3) + (n1 & 7)] = bf16r(gelu_f(val));
      }
    }
  {
    int r = tid >> 1, half = tid & 1;
    const unsigned short* sB = Wo2T + (size_t)r * 128 + half * 64;
#pragma unroll
    for (int q = 0; q < 8; q++) {
      int c8 = half * 8 + q;
      *(uint4*)&Bs[r * 128 + ((c8 ^ (r & 15)) << 3)] = *(const uint4*)(sB + q * 8);
    }
  }
  __syncthreads();
  facc a2[2][8];
#pragma unroll
  for (int a = 0; a < 2; a++)
#pragma unroll
    for (int bq = 0; bq < 8; bq++) a2[a][bq] = zf;
#pragma unroll
  for (int k0 = 0; k0 < 4; k0++) {
    bfrag av[2];
#pragma unroll
    for (int it = 0; it < 2; it++) {
      int row = (w + it * 4) * 16 + l16;
      av[it] = *(const bfrag*)&As[row * 128 + (((k0 * 4 + quad) ^ l16) << 3)];
    }
#pragma unroll
    for (int nt = 0; nt < 8; nt++) {
      int row = nt * 16 + l16;
      bfrag bv = *(const bfrag*)&Bs[row * 128 + (((k0 * 4 + quad) ^ l16) << 3)];
      a2[0][nt] = __builtin_amdgcn_mfma_f32_16x16x32_bf16(av[0], bv, a2[0][nt], 0, 0, 0);
      a2[1][nt] = __builtin_amdgcn_mfma_f32_16x16x32_bf16(av[1], bv, a2[1][nt], 0, 0, 0);
    }
  }
#pragma unroll
  for (int it = 0; it < 2; it++)
#pragma unroll
    for (int nt = 0; nt < 8; nt++) {
      int n2 = nt * 16 + l16;
#pragma unroll
      for (int rr = 0; rr < 4; rr++) {
        int l = (w + it * 4) * 16 + quad * 4 + rr;
        out[((size_t)(b * 16384 + i * 128 + l)) * 128 + n2] = a2[it][nt][rr];
      }
    }
}

extern "C" void kernel_launch(void* const* d_in, const int* in_sizes, int n_in,
                              void* d_out, int out_size, void* d_ws, size_t ws_size,
                              hipStream_t stream) {
  const float* u = (const float*)d_in[0];
  const float* pos_x = (const float*)d_in[1];
  const float* pos_y = (const float*)d_in[2];
  const float* ln_g = (const float*)d_in[3];
  const float* ln_b = (const float*)d_in[4];
  const float* Wv = (const float*)d_in[5];
  const float* Win = (const float*)d_in[6];
  const float* px_Win = (const float*)d_in[7];
  const float* px_g = (const float*)d_in[8];
  const float* px_b = (const float*)d_in[9];
  const float* px_W1 = (const float*)d_in[10];
  const float* px_b1 = (const float*)d_in[11];
  const float* px_W2 = (const float*)d_in[12];
  const float* px_b2 = (const float*)d_in[13];
  const float* py_Win = (const float*)d_in[14];
  const float* py_g = (const float*)d_in[15];
  const float* py_b = (const float*)d_in[16];
  const float* py_W1 = (const float*)d_in[17];
  const float* py_b1 = (const float*)d_in[18];
  const float* py_W2 = (const float*)d_in[19];
  const float* py_b2 = (const float*)d_in[20];
  const float* Wqk_x = (const float*)d_in[21];
  const float* Wqk_y = (const float*)d_in[22];
  const float* Wo1 = (const float*)d_in[23];
  const float* Wo2 = (const float*)d_in[24];
  float* out = (float*)d_out;

  const size_t NEED = 44868736;  // floats (~180 MB); harness ws is 256 MiB
  if (ws_size < NEED * sizeof(float)) return;
  float* ws = (float*)d_ws;
  unsigned short* un_bf = (unsigned short*)ws;               // [65536][128]
  unsigned short* vT    = (unsigned short*)(ws + 4194304);   // [512][65536]
  unsigned short* ttp   = (unsigned short*)(ws + 20971520);  // [32][64][128][128]
  float* small = ws + 37748736;
  float* Wcx   = small + 131072;        // 16384
  float* Wcy   = small + 147456;        // 16384
  float* ux    = small + 163840;        // 32768
  float* uy    = small + 196608;        // 32768
  float* qkx   = small + 229376;        // 1572864
  float* qky   = small + 1802240;       // 1572864
  float* tabx  = small + 3375104;       // 24576 (128*96 float2)
  float* taby  = small + 3399680;       // 24576
  unsigned short* kx_bf = (unsigned short*)(small + 6520832);  // 524288 el
  unsigned short* ky_bf = (unsigned short*)(small + 6782976);  // 524288 el
  unsigned short* WvT   = (unsigned short*)(small + 7045120);  // 65536 el
  unsigned short* Wo1T  = (unsigned short*)(small + 7077888);  // 65536 el
  unsigned short* Wo2T  = (unsigned short*)(small + 7110656);  // 16384 el
  float* sbuf  = small + 7118848;       // 512 (+512 s2buf, contiguous)
  float* s2buf = small + 7119360;       // 512
  float* scol  = small + 7119872;       // 128

  // Phase A (4 launches; memset folded into k_lnw)
  k_lnw<<<17066, 256, 0, stream>>>(u, ln_g, ln_b, un_bf, Wv, Wo1, Wo2,
                                   WvT, Wo1T, Wo2T, scol,
                                   Win, px_Win, py_Win, Wcx, Wcy,
                                   pos_x, pos_y, tabx, taby, sbuf);
  k_pvt<<<1024, 256, 0, stream>>>(WvT, un_bf, vT,
                                  Wcx, Wcy, px_g, py_g, px_b, py_b,
                                  px_W1, py_W1, px_b1, py_b1, px_W2, py_W2,
                                  px_b2, py_b2, ux, uy);
  k_gemmz<<<dim3(48, 8, 2), 256, 0, stream>>>(ux, Wqk_x, qkx, uy, Wqk_y, qky,
                                              64, 64, 3072, 3072);
  k_qkt2<<<dim3(2, 2, 64), 512, 0, stream>>>(qkx, qky, tabx, taby, kx_bf, ky_bf);

  // Phase B (2 launches)
  k_fuse12<<<512, 256, 0, stream>>>(kx_bf, ky_bf, vT, ttp, sbuf, s2buf);
  k_tail2<<<512, 256, 0, stream>>>(ttp, Wo1T, Wo2T, out, sbuf, s2buf, scol);
}